// Round 13
// baseline (432.417 us; speedup 1.0000x reference)
//
#include <hip/hip_runtime.h>

// BeamDelay2AntFreq: (256,32,8,4,2,48) complex -> ifft4(V) -> ifft8(H) -> fft48(t),
// fftshifts folded into (-1)^{h+v+f}; ortho norm 1/sqrt(1536).
// OUTPUT LAYOUT (decoded R11+R12): interleaved pairs, IMAG FIRST:
// bf16[2k] = imag(z_k), bf16[2k+1] = real(z_k); z in (b,c,row=(h*4+v)*2+p,f) order.

namespace {

constexpr int RP = 52;                 // padded LDS row stride (floats)
constexpr float NORM = 0.02551551815399144f;  // 1/sqrt(1536)

constexpr float COS48[48] = {
  1.0f,        0.99144486f,  0.96592583f,  0.92387953f,  0.86602540f,  0.79335334f,
  0.70710678f, 0.60876143f,  0.5f,         0.38268343f,  0.25881905f,  0.13052619f,
  0.0f,       -0.13052619f, -0.25881905f, -0.38268343f, -0.5f,        -0.60876143f,
 -0.70710678f,-0.79335334f, -0.86602540f, -0.92387953f, -0.96592583f, -0.99144486f,
 -1.0f,       -0.99144486f, -0.96592583f, -0.92387953f, -0.86602540f, -0.79335334f,
 -0.70710678f,-0.60876143f, -0.5f,        -0.38268343f, -0.25881905f, -0.13052619f,
  0.0f,        0.13052619f,  0.25881905f,  0.38268343f,  0.5f,         0.60876143f,
  0.70710678f, 0.79335334f,  0.86602540f,  0.92387953f,  0.96592583f,  0.99144486f
};
constexpr float SIN48[48] = {
  0.0f,        0.13052619f,  0.25881905f,  0.38268343f,  0.5f,         0.60876143f,
  0.70710678f, 0.79335334f,  0.86602540f,  0.92387953f,  0.96592583f,  0.99144486f,
  1.0f,        0.99144486f,  0.96592583f,  0.92387953f,  0.86602540f,  0.79335334f,
  0.70710678f, 0.60876143f,  0.5f,         0.38268343f,  0.25881905f,  0.13052619f,
  0.0f,       -0.13052619f, -0.25881905f, -0.38268343f, -0.5f,        -0.60876143f,
 -0.70710678f,-0.79335334f, -0.86602540f, -0.92387953f, -0.96592583f, -0.99144486f,
 -1.0f,       -0.99144486f, -0.96592583f, -0.92387953f, -0.86602540f, -0.79335334f,
 -0.70710678f,-0.60876143f, -0.5f,        -0.38268343f, -0.25881905f, -0.13052619f
};

constexpr float W8R_TAB[8] = {1.0f, 0.70710678f, 0.0f, -0.70710678f, -1.0f, -0.70710678f, 0.0f, 0.70710678f};
constexpr float W8I_TAB[8] = {0.0f, 0.70710678f, 1.0f,  0.70710678f,  0.0f, -0.70710678f, -1.0f, -0.70710678f};

__device__ __forceinline__ unsigned bf16_rne(float x) {
  unsigned u = __float_as_uint(x);
  u += 0x7FFFu + ((u >> 16) & 1u);
  return u >> 16;
}

__device__ __forceinline__ void ld4(const float* p, float* d) {
  float4 v = *reinterpret_cast<const float4*>(p);
  d[0] = v.x; d[1] = v.y; d[2] = v.z; d[3] = v.w;
}
__device__ __forceinline__ void st4(float* p, const float* s) {
  *reinterpret_cast<float4*>(p) = make_float4(s[0], s[1], s[2], s[3]);
}

__global__ __launch_bounds__(256, 2)
void bd2af_kernel(const float* __restrict__ xr, const float* __restrict__ xi,
                  unsigned* __restrict__ out, int nbc) {
  __shared__ __align__(16) float Ar[64 * RP], Ai[64 * RP];   // X, then Y (reused)
  __shared__ __align__(16) float Br[64 * RP], Bi[64 * RP];   // T1; Br reused as out staging
  __shared__ float w8r[8], w8i[8];

  const int tid = threadIdx.x;
  const int bc = blockIdx.x;
  if (bc >= nbc) return;

  if (tid < 8) { w8r[tid] = W8R_TAB[tid]; w8i[tid] = W8I_TAB[tid]; }

  // ---- global -> LDS (rows of 48 padded to 52) ----
  {
    const float4* gr = reinterpret_cast<const float4*>(xr) + (size_t)bc * 768;
    const float4* gi = reinterpret_cast<const float4*>(xi) + (size_t)bc * 768;
#pragma unroll
    for (int k = 0; k < 3; ++k) {
      const int o4 = tid + 256 * k;
      const float4 vr = gr[o4];
      const float4 vi = gi[o4];
      const int o = o4 * 4;
      const int row = o / 48;              // float4 never crosses a row (48 % 4 == 0)
      const int a = row * RP + (o - row * 48);
      *reinterpret_cast<float4*>(&Ar[a]) = vr;
      *reinterpret_cast<float4*>(&Ai[a]) = vi;
    }
  }
  __syncthreads();

  const int c  = tid & 3;          // t/freq chunk
  const int t0 = c * 12;
  const int p  = (tid >> 2) & 1;
  const int vq = (tid >> 3) & 3;
  const int hq = tid >> 5;

  // ---- V pass: T1[H][v'][p][t] = sum_V X[H][V][p][t] * i^(V*v') ----
  {
    float ar[12], ai2[12];
#pragma unroll
    for (int k = 0; k < 12; ++k) { ar[k] = 0.f; ai2[k] = 0.f; }
#pragma unroll
    for (int V = 0; V < 4; ++V) {
      const int m = (V * vq) & 3;
      const float wr = (m == 0) ? 1.f : ((m == 2) ? -1.f : 0.f);
      const float wi = (m == 1) ? 1.f : ((m == 3) ? -1.f : 0.f);
      const int rowi = (hq * 4 + V) * 2 + p;
      const float* sr = &Ar[rowi * RP + t0];
      const float* si = &Ai[rowi * RP + t0];
      float yr[12], yi4[12];
      ld4(sr, yr); ld4(sr + 4, yr + 4); ld4(sr + 8, yr + 8);
      ld4(si, yi4); ld4(si + 4, yi4 + 4); ld4(si + 8, yi4 + 8);
#pragma unroll
      for (int k = 0; k < 12; ++k) {
        ar[k]  += yr[k] * wr - yi4[k] * wi;
        ai2[k] += yr[k] * wi + yi4[k] * wr;
      }
    }
    const int rowo = (hq * 4 + vq) * 2 + p;
    float* dr = &Br[rowo * RP + t0];
    float* di = &Bi[rowo * RP + t0];
    st4(dr, ar); st4(dr + 4, ar + 4); st4(dr + 8, ar + 8);
    st4(di, ai2); st4(di + 4, ai2 + 4); st4(di + 8, ai2 + 8);
  }
  __syncthreads();

  // ---- H pass: Y[h'][v'][p][t] = (-1)^{h'+v'} * sum_H T1[H][v'][p][t] * w8[(H*h')%8] ----
  {
    float ar[12], ai2[12];
#pragma unroll
    for (int k = 0; k < 12; ++k) { ar[k] = 0.f; ai2[k] = 0.f; }
#pragma unroll
    for (int H = 0; H < 8; ++H) {
      const int m = (H * hq) & 7;
      const float wr = w8r[m];
      const float wi = w8i[m];
      const int rowi = (H * 4 + vq) * 2 + p;
      const float* sr = &Br[rowi * RP + t0];
      const float* si = &Bi[rowi * RP + t0];
      float yr[12], yi4[12];
      ld4(sr, yr); ld4(sr + 4, yr + 4); ld4(sr + 8, yr + 8);
      ld4(si, yi4); ld4(si + 4, yi4 + 4); ld4(si + 8, yi4 + 8);
#pragma unroll
      for (int k = 0; k < 12; ++k) {
        ar[k]  += yr[k] * wr - yi4[k] * wi;
        ai2[k] += yr[k] * wi + yi4[k] * wr;
      }
    }
    const float sgn = ((hq + vq) & 1) ? -1.f : 1.f;
    const int rowo = (hq * 4 + vq) * 2 + p;
    float* dr = &Ar[rowo * RP + t0];
    float* di = &Ai[rowo * RP + t0];
#pragma unroll
    for (int k = 0; k < 12; ++k) { ar[k] *= sgn; ai2[k] *= sgn; }
    st4(dr, ar); st4(dr + 4, ar + 4); st4(dr + 8, ar + 8);
    st4(di, ai2); st4(di + 4, ai2 + 4); st4(di + 8, ai2 + 8);
  }
  __syncthreads();

  // ---- time DFT + pack: dword per complex element = im | (re<<16) ----
  {
    const int r = tid >> 2;
    float zr[48], zi[48];
#pragma unroll
    for (int m = 0; m < 12; ++m) {
      ld4(&Ar[r * RP + 4 * m], &zr[4 * m]);
      ld4(&Ai[r * RP + 4 * m], &zi[4 * m]);
    }
    const float w1r = (c == 0) ? 1.f : ((c == 2) ? -1.f : 0.f);
    const float w1i = (c == 1) ? -1.f : ((c == 3) ? 1.f : 0.f);
    const float w2  = (c & 1) ? -1.f : 1.f;
#pragma unroll
    for (int t = 0; t < 48; ++t) {
      const int m = t & 3;
      if (m == 1) {
        const float a = zr[t], b = zi[t];
        zr[t] = a * w1r - b * w1i;  zi[t] = a * w1i + b * w1r;
      } else if (m == 2) {
        zr[t] *= w2;  zi[t] *= w2;
      } else if (m == 3) {
        const float a = zr[t], b = zi[t];
        zr[t] = a * w1r + b * w1i;  zi[t] = b * w1r - a * w1i;
      }
    }
    float fr[12], fi[12];
#pragma unroll
    for (int j = 0; j < 12; ++j) { fr[j] = 0.f; fi[j] = 0.f; }
#pragma unroll
    for (int t = 0; t < 48; ++t) {
#pragma unroll
      for (int j = 0; j < 12; ++j) {
        const int k = (t * j) % 48;
        const float twr = COS48[k];
        const float twi = -SIN48[k];
        fr[j] += zr[t] * twr - zi[t] * twi;
        fi[j] += zr[t] * twi + zi[t] * twr;
      }
    }
    // staging: dword index r*48 + f, f = 12c + j; IMAG low 16, REAL high 16
    unsigned* obuf = reinterpret_cast<unsigned*>(Br);
#pragma unroll
    for (int j = 0; j < 12; ++j) {
      const float s = (j & 1) ? -NORM : NORM;   // (-1)^f = (-1)^j since f = 12c+j
      obuf[r * 48 + c * 12 + j] = bf16_rne(fi[j] * s) | (bf16_rne(fr[j] * s) << 16);
    }
  }
  __syncthreads();

  // ---- coalesced store: 3072 dwords = 768 uint4 per block ----
  {
    const uint4* ob = reinterpret_cast<const uint4*>(Br);
    uint4* og = reinterpret_cast<uint4*>(out) + (size_t)bc * 768;
#pragma unroll
    for (int k = 0; k < 3; ++k) {
      const int o4 = tid + 256 * k;
      og[o4] = ob[o4];
    }
  }
}

} // namespace

extern "C" void kernel_launch(void* const* d_in, const int* in_sizes, int n_in,
                              void* d_out, int out_size, void* d_ws, size_t ws_size,
                              hipStream_t stream) {
  const float* xr = (const float*)d_in[0];   // dict order: x_real first
  const float* xi = (const float*)d_in[1];
  unsigned* out = (unsigned*)d_out;          // dword = im(bf16) | re(bf16)<<16
  const int nbc = in_sizes[0] / 3072;        // 8192 blocks of (8*4*2*48)
  bd2af_kernel<<<nbc, 256, 0, stream>>>(xr, xi, out, nbc);
}